// Round 2
// baseline (574.881 us; speedup 1.0000x reference)
//
#include <hip/hip_runtime.h>
#include <cstdint>
#include <cstddef>

// Paged GQA flash-decode attention, fp32, split-KV two-pass, software-pipelined.
// B=16 H=32 D=128 T=4096 KVH=8 G=4.  Memory-bound: ~268MB KV traffic -> ~43us floor.

#define NB 16
#define NH 32
#define HD 128
#define NT 4096
#define NKVH 8
#define NG 4
#define NSPLIT 16
#define CHUNK (NT / NSPLIT)      // 256 tokens per block
#define TILE_T 16                // tokens per wave-tile
#define NWAVE 4
#define ROW 132                  // padded LDS row stride (floats)
#define PART_STRIDE 520          // per-(b,kvh,split): o[4][128] + m[4] + l[4]
#define SCALE_F 0.08838834764831845f

// Compile-time ordering fence for wave-synchronous LDS use (DS ops are in-order per wave).
__device__ __forceinline__ void wave_sync() {
    __builtin_amdgcn_wave_barrier();
    __asm__ volatile("" ::: "memory");
}

__global__ __launch_bounds__(256) void attn_partial_kernel(
    const float* __restrict__ q,
    const float* __restrict__ kc,
    const float* __restrict__ vc,
    const int*   __restrict__ kv_lens,
    const int*   __restrict__ btab,
    float*       __restrict__ part)
{
    __shared__ float q_lds[NG][ROW];                    // 2112 B (q pre-scaled by SCALE)
    __shared__ float kv_lds[NWAVE][TILE_T][ROW];        // 33792 B (K, then reused for V)
    __shared__ float p_lds[NWAVE][TILE_T][NG];          // 1024 B
    __shared__ float a_lds[NWAVE][NG];                  // 64 B
    __shared__ float ml_lds[NWAVE][NG][2];              // 128 B

    const int bid = blockIdx.x;                 // = (b*NKVH + kvh)*NSPLIT + c
    const int c   = bid % NSPLIT;
    const int kvh = (bid / NSPLIT) % NKVH;
    const int b   = bid / (NSPLIT * NKVH);
    const int tid  = threadIdx.x;
    const int w    = tid >> 6;
    const int lane = tid & 63;

    const int kv_len = kv_lens[b];
    const int t0c = c * CHUNK;
    const int t1c = min(t0c + CHUNK, kv_len);

    float* pb = part + (size_t)bid * PART_STRIDE;

    if (t0c >= kv_len) {
        for (int i = tid; i < PART_STRIDE; i += 256)
            pb[i] = (i >= 512 && i < 516) ? -1e30f : 0.0f;
        return;
    }

    // stage q (pre-scaled) into LDS
    {
        int g  = tid >> 6;
        int dd = (tid & 63) * 2;
        const float* qp = q + ((size_t)(b * NH + kvh * NG + g)) * HD + dd;
        q_lds[g][dd]     = qp[0] * SCALE_F;
        q_lds[g][dd + 1] = qp[1] * SCALE_F;
    }
    __syncthreads();

    const int half = lane >> 5;       // staging: which of 2 rows this half-wave loads
    const int d4   = lane & 31;       // staging: float4 index within row
    const int t_s  = lane & 15;       // score layout: token within tile
    const int seg  = lane >> 4;       // score layout: 32-float d-segment; also g for softmax state
    const int dp   = lane * 2;        // PV layout: d-pair owned by lane

    const float* kbase = kc + (size_t)kvh * HD;
    const float* vbase = vc + (size_t)kvh * HD;
    const int*   bt_b  = btab + b * NT;

    float m_g = -1e30f;               // per-seg-group state (g = seg)
    float l_g = 0.0f;
    float o00=0,o01=0,o10=0,o11=0,o20=0,o21=0,o30=0,o31=0;  // o[g][2], PV layout

    float4 ka[8], kb_[8], vv[8];      // K double-buffer + V buffer (registers)

    int t0 = t0c + w * TILE_T;
    // prologue: K loads for this wave's first tile
    if (t0 < t1c) {
        #pragma unroll
        for (int r = 0; r < 8; ++r) {
            int t = t0 + r * 2 + half;
            int page = bt_b[(t < t1c) ? t : t0c];      // btab folded into addr chain (no shfl)
            ka[r] = *((const float4*)(kbase + (size_t)page * (NKVH * HD)) + d4);
        }
    }

    for (; t0 < t1c; t0 += NWAVE * TILE_T) {
        // issue V loads for current tile (latency overlaps scores below)
        #pragma unroll
        for (int r = 0; r < 8; ++r) {
            int t = t0 + r * 2 + half;
            int page = bt_b[(t < t1c) ? t : t0c];
            vv[r] = *((const float4*)(vbase + (size_t)page * (NKVH * HD)) + d4);
        }
        // K regs -> LDS
        #pragma unroll
        for (int r = 0; r < 8; ++r)
            *(float4*)&kv_lds[w][r * 2 + half][d4 * 4] = ka[r];

        // prefetch NEXT tile's K (latency overlaps scores+softmax+PV of this tile)
        const int t0n = t0 + NWAVE * TILE_T;
        if (t0n < t1c) {
            #pragma unroll
            for (int r = 0; r < 8; ++r) {
                int t = t0n + r * 2 + half;
                int page = bt_b[(t < t1c) ? t : t0c];
                kb_[r] = *((const float4*)(kbase + (size_t)page * (NKVH * HD)) + d4);
            }
        }
        wave_sync();

        // scores: lane (t_s, seg) -> partial dots for ALL 4 g over its 32-float segment
        float s0=0,s1=0,s2=0,s3=0;
        #pragma unroll
        for (int i = 0; i < 8; ++i) {
            float4 kk = *(const float4*)&kv_lds[w][t_s][seg * 32 + i * 4];
            float4 q0 = *(const float4*)&q_lds[0][seg * 32 + i * 4];
            float4 q1 = *(const float4*)&q_lds[1][seg * 32 + i * 4];
            float4 q2 = *(const float4*)&q_lds[2][seg * 32 + i * 4];
            float4 q3 = *(const float4*)&q_lds[3][seg * 32 + i * 4];
            s0 = fmaf(kk.x,q0.x,fmaf(kk.y,q0.y,fmaf(kk.z,q0.z,fmaf(kk.w,q0.w,s0))));
            s1 = fmaf(kk.x,q1.x,fmaf(kk.y,q1.y,fmaf(kk.z,q1.z,fmaf(kk.w,q1.w,s1))));
            s2 = fmaf(kk.x,q2.x,fmaf(kk.y,q2.y,fmaf(kk.z,q2.z,fmaf(kk.w,q2.w,s2))));
            s3 = fmaf(kk.x,q3.x,fmaf(kk.y,q3.y,fmaf(kk.z,q3.z,fmaf(kk.w,q3.w,s3))));
        }
        // reduce over the 4 d-segments (lanes xor 16,32); then keep g = seg
        s0 += __shfl_xor(s0, 16); s0 += __shfl_xor(s0, 32);
        s1 += __shfl_xor(s1, 16); s1 += __shfl_xor(s1, 32);
        s2 += __shfl_xor(s2, 16); s2 += __shfl_xor(s2, 32);
        s3 += __shfl_xor(s3, 16); s3 += __shfl_xor(s3, 32);
        float s = (seg == 0) ? s0 : (seg == 1) ? s1 : (seg == 2) ? s2 : s3;
        if (t0 + t_s >= t1c) s = -1e30f;            // tail mask

        // online softmax over 16 tokens (lanes xor 1,2,4,8 within the seg group)
        float tmax = s;
        #pragma unroll
        for (int off = 1; off < 16; off <<= 1)
            tmax = fmaxf(tmax, __shfl_xor(tmax, off));
        float m_new = fmaxf(m_g, tmax);
        float alpha = __expf(m_g - m_new);
        float p     = __expf(s - m_new);
        float tsum = p;
        #pragma unroll
        for (int off = 1; off < 16; off <<= 1)
            tsum += __shfl_xor(tsum, off);
        l_g = l_g * alpha + tsum;
        m_g = m_new;

        p_lds[w][t_s][seg] = p;
        if (t_s == 0) a_lds[w][seg] = alpha;
        wave_sync();

        // V regs -> LDS over the K region (same-wave DS ordering makes WAR safe)
        #pragma unroll
        for (int r = 0; r < 8; ++r)
            *(float4*)&kv_lds[w][r * 2 + half][d4 * 4] = vv[r];
        wave_sync();

        // PV: lane owns d-pair dp; p broadcast per token
        float a0 = a_lds[w][0], a1 = a_lds[w][1], a2 = a_lds[w][2], a3 = a_lds[w][3];
        o00 *= a0; o01 *= a0; o10 *= a1; o11 *= a1;
        o20 *= a2; o21 *= a2; o30 *= a3; o31 *= a3;
        #pragma unroll
        for (int t = 0; t < TILE_T; ++t) {
            float2 vvv = *(const float2*)&kv_lds[w][t][dp];
            float4 pp  = *(const float4*)&p_lds[w][t][0];   // broadcast
            o00 = fmaf(pp.x, vvv.x, o00); o01 = fmaf(pp.x, vvv.y, o01);
            o10 = fmaf(pp.y, vvv.x, o10); o11 = fmaf(pp.y, vvv.y, o11);
            o20 = fmaf(pp.z, vvv.x, o20); o21 = fmaf(pp.z, vvv.y, o21);
            o30 = fmaf(pp.w, vvv.x, o30); o31 = fmaf(pp.w, vvv.y, o31);
        }
        wave_sync();

        // rotate K double-buffer
        #pragma unroll
        for (int r = 0; r < 8; ++r) ka[r] = kb_[r];
    }

    // cross-wave combine within block: each wave dumps into ITS OWN kv_lds region
    {
        float* ow = &kv_lds[w][0][0];
        ow[0 * HD + dp] = o00; ow[0 * HD + dp + 1] = o01;
        ow[1 * HD + dp] = o10; ow[1 * HD + dp + 1] = o11;
        ow[2 * HD + dp] = o20; ow[2 * HD + dp + 1] = o21;
        ow[3 * HD + dp] = o30; ow[3 * HD + dp + 1] = o31;
        if (t_s == 0) { ml_lds[w][seg][0] = m_g; ml_lds[w][seg][1] = l_g; }
    }
    __syncthreads();

    {
        int g  = tid >> 6;
        int d2 = (tid & 63) * 2;
        float M = fmaxf(fmaxf(ml_lds[0][g][0], ml_lds[1][g][0]),
                        fmaxf(ml_lds[2][g][0], ml_lds[3][g][0]));
        float L = 0.0f, O0 = 0.0f, O1 = 0.0f;
        #pragma unroll
        for (int wv = 0; wv < NWAVE; ++wv) {
            float sc = __expf(ml_lds[wv][g][0] - M);   // empty wave contributes 0
            L  += ml_lds[wv][g][1] * sc;
            const float* owv = &kv_lds[wv][0][0];
            O0 += owv[g * HD + d2]     * sc;
            O1 += owv[g * HD + d2 + 1] * sc;
        }
        pb[g * HD + d2]     = O0;      // unnormalized partial
        pb[g * HD + d2 + 1] = O1;
        if ((tid & 63) == 0) { pb[512 + g] = M; pb[516 + g] = L; }
    }
}

__global__ __launch_bounds__(256) void attn_combine_kernel(
    const float* __restrict__ part, float* __restrict__ out)
{
    const int bid = blockIdx.x;        // b*NKVH + kvh
    const int tid = threadIdx.x;
    const int g  = tid >> 6;
    const int d2 = (tid & 63) * 2;
    const int b   = bid / NKVH;
    const int kvh = bid % NKVH;
    const float* pb = part + (size_t)bid * NSPLIT * PART_STRIDE;

    float M = -1e30f;
    #pragma unroll
    for (int cc = 0; cc < NSPLIT; ++cc)
        M = fmaxf(M, pb[cc * PART_STRIDE + 512 + g]);
    float L = 0.0f, O0 = 0.0f, O1 = 0.0f;
    #pragma unroll
    for (int cc = 0; cc < NSPLIT; ++cc) {
        float mc = pb[cc * PART_STRIDE + 512 + g];
        float sc = __expf(mc - M);                    // empty chunk -> 0
        L  += pb[cc * PART_STRIDE + 516 + g] * sc;
        O0 += pb[cc * PART_STRIDE + g * HD + d2]     * sc;
        O1 += pb[cc * PART_STRIDE + g * HD + d2 + 1] * sc;
    }
    float inv = 1.0f / L;                             // chunk 0 always non-empty -> L>0
    const int h = kvh * NG + g;
    out[((size_t)b * NH + h) * HD + d2]     = O0 * inv;
    out[((size_t)b * NH + h) * HD + d2 + 1] = O1 * inv;
}

extern "C" void kernel_launch(void* const* d_in, const int* in_sizes, int n_in,
                              void* d_out, int out_size, void* d_ws, size_t ws_size,
                              hipStream_t stream)
{
    const float* q   = (const float*)d_in[0];
    const float* kc  = (const float*)d_in[1];
    const float* vc  = (const float*)d_in[2];
    const int*   kvl = (const int*)d_in[3];
    const int*   bt  = (const int*)d_in[4];
    float* part = (float*)d_ws;   // 16*8*16*520*4 B = 4.06 MB of ws used

    attn_partial_kernel<<<NB * NKVH * NSPLIT, 256, 0, stream>>>(q, kc, vc, kvl, bt, part);
    attn_combine_kernel<<<NB * NKVH, 256, 0, stream>>>(part, (float*)d_out);
}

// Round 3
// 470.867 us; speedup vs baseline: 1.2209x; 1.2209x over previous
//
#include <hip/hip_runtime.h>
#include <cstdint>
#include <cstddef>

// Paged GQA flash-decode attention, fp32, split-KV two-pass.
// R3: global_load_lds staging (no VGPR round-trip / no spill), fixed-role
// K/V LDS double-buffer pipelined with explicit vmcnt waits, XOR-swizzled
// LDS chunks (glds needs unpadded rows), q in registers, balanced chunks.

#define NB 16
#define NH 32
#define HD 128
#define NT 4096
#define NKVH 8
#define NG 4
#define NSPLIT 16
#define TILE_T 16
#define NWAVE 4
#define PART_STRIDE 520          // o[4][128] + m[4] + l[4]
#define SCALE_F 0.08838834764831845f
#define KVROW (NKVH * HD)        // floats per page row block = 1024

__device__ __forceinline__ void fence_sched() { __asm__ volatile("" ::: "memory"); }
// s_waitcnt imm: [3:0]=vmcnt lo, [6:4]=expcnt, [11:8]=lgkmcnt, [15:14]=vmcnt hi
#define WAIT_VM8() { __builtin_amdgcn_s_waitcnt(0x0F78); fence_sched(); }
#define WAIT_VM0() { __builtin_amdgcn_s_waitcnt(0x0F70); fence_sched(); }

__device__ __forceinline__ void glds16(const float* g, float* l) {
    __builtin_amdgcn_global_load_lds(
        (__attribute__((address_space(1))) void*)g,
        (__attribute__((address_space(3))) void*)l,
        16, 0, 0);
}

__global__ __launch_bounds__(256, 2) void attn_partial_kernel(
    const float* __restrict__ q,
    const float* __restrict__ kc,
    const float* __restrict__ vc,
    const int*   __restrict__ kv_lens,
    const int*   __restrict__ btab,
    float*       __restrict__ part)
{
    __shared__ __align__(16) float kx[NWAVE][TILE_T][HD];   // K tiles (swizzled), 32 KB
    __shared__ __align__(16) float ky[NWAVE][TILE_T][HD];   // V tiles (swizzled), 32 KB
    __shared__ __align__(16) float p_lds[NWAVE][TILE_T][NG];
    __shared__ __align__(16) float a_lds[NWAVE][NG];
    __shared__ __align__(16) float ml_lds[NWAVE][NG][2];
    // ~66.3 KB -> 2 blocks/CU (8 waves/CU)

    const int bid = blockIdx.x;                 // (b*NKVH + kvh)*NSPLIT + c
    const int c   = bid % NSPLIT;
    const int kvh = (bid / NSPLIT) % NKVH;
    const int b   = bid / (NSPLIT * NKVH);
    const int tid  = threadIdx.x;
    const int w    = tid >> 6;
    const int lane = tid & 63;

    const int kv_len = kv_lens[b];
    const int clen = (kv_len + NSPLIT - 1) / NSPLIT;   // balanced per-seq chunks
    const int t0c = c * clen;
    const int t1c = min(t0c + clen, kv_len);

    float* pb = part + (size_t)bid * PART_STRIDE;

    if (t0c >= kv_len) {       // only when kv_len < NSPLIT
        for (int i = tid; i < PART_STRIDE; i += 256)
            pb[i] = (i >= 512 && i < 516) ? -1e30f : 0.0f;
        return;
    }

    const int half = lane >> 5;       // staging: row parity this half-wave loads
    const int cc   = lane & 31;       // staging: chunk (16B) index within row
    const int t_s  = lane & 15;       // score layout: token in tile
    const int seg  = lane >> 4;       // score layout: 32-float d-segment (= g after reduce)
    const int t7   = t_s & 7;
    const int dp   = lane * 2;        // PV layout: d-pair owned by lane

    // q fragment in registers: this lane's 32-float segment for all 4 g, pre-scaled
    float4 qreg[NG][8];
    {
        const float* qb = q + ((size_t)(b * NH + kvh * NG)) * HD + seg * 32;
        #pragma unroll
        for (int g = 0; g < NG; ++g) {
            #pragma unroll
            for (int i = 0; i < 8; ++i) {
                float4 t = *((const float4*)(qb + g * HD) + i);
                qreg[g][i] = make_float4(t.x * SCALE_F, t.y * SCALE_F,
                                         t.z * SCALE_F, t.w * SCALE_F);
            }
        }
    }

    const float* kbase = kc + (size_t)kvh * HD;
    const float* vbase = vc + (size_t)kvh * HD;
    const int*   bt_b  = btab + b * NT;

    // swizzled within-row source float offset, per (r & 3):  (cc ^ (R&7))*4, R=2r+half
    int csw[4];
    #pragma unroll
    for (int j = 0; j < 4; ++j)
        csw[j] = ((cc ^ ((2 * j + half) & 7)) << 2);

    float m_g = -1e30f, l_g = 0.0f;
    float o00=0,o01=0,o10=0,o11=0,o20=0,o21=0,o30=0,o31=0;

    int t0 = t0c + w * TILE_T;
    if (t0 < t1c) {
        int pgc[8];
        #pragma unroll
        for (int r = 0; r < 8; ++r) {
            int t = t0 + r * 2 + half;
            pgc[r] = bt_b[(t < t1c) ? t : t0c];
        }
        fence_sched();
        #pragma unroll
        for (int r = 0; r < 8; ++r)          // K0 -> X
            glds16(kbase + (size_t)pgc[r] * KVROW + csw[r & 3], &kx[w][r * 2][0]);
        fence_sched();
        #pragma unroll
        for (int r = 0; r < 8; ++r)          // V0 -> Y
            glds16(vbase + (size_t)pgc[r] * KVROW + csw[r & 3], &ky[w][r * 2][0]);
        fence_sched();
    }

    for (; t0 < t1c; t0 += NWAVE * TILE_T) {
        const int t0n = t0 + NWAVE * TILE_T;
        const bool has_next = (t0n < t1c);

        WAIT_VM8();     // K_i landed (V_i's 8 still in flight)

        // scores: lane (t_s, seg) partial-dots all 4 g over its 32-float segment
        float s0 = 0, s1 = 0, s2 = 0, s3 = 0;
        #pragma unroll
        for (int i = 0; i < 8; ++i) {
            int pc4 = (((seg * 8 + i) ^ t7) << 2);
            float4 kk = *(const float4*)&kx[w][t_s][pc4];
            float4 q0 = qreg[0][i], q1 = qreg[1][i], q2 = qreg[2][i], q3 = qreg[3][i];
            s0 = fmaf(kk.x,q0.x,fmaf(kk.y,q0.y,fmaf(kk.z,q0.z,fmaf(kk.w,q0.w,s0))));
            s1 = fmaf(kk.x,q1.x,fmaf(kk.y,q1.y,fmaf(kk.z,q1.z,fmaf(kk.w,q1.w,s1))));
            s2 = fmaf(kk.x,q2.x,fmaf(kk.y,q2.y,fmaf(kk.z,q2.z,fmaf(kk.w,q2.w,s2))));
            s3 = fmaf(kk.x,q3.x,fmaf(kk.y,q3.y,fmaf(kk.z,q3.z,fmaf(kk.w,q3.w,s3))));
        }
        s0 += __shfl_xor(s0, 16); s0 += __shfl_xor(s0, 32);
        s1 += __shfl_xor(s1, 16); s1 += __shfl_xor(s1, 32);
        s2 += __shfl_xor(s2, 16); s2 += __shfl_xor(s2, 32);
        s3 += __shfl_xor(s3, 16); s3 += __shfl_xor(s3, 32);
        float s = (seg == 0) ? s0 : (seg == 1) ? s1 : (seg == 2) ? s2 : s3;
        if (t0 + t_s >= t1c) s = -1e30f;

        // prefetch next tile's page ids (cheap btab loads; drained by WAIT_VM0)
        int pgn[8];
        if (has_next) {
            #pragma unroll
            for (int r = 0; r < 8; ++r) {
                int t = t0n + r * 2 + half;
                pgn[r] = bt_b[(t < t1c) ? t : t0c];
            }
        }

        // online softmax over 16 tokens per g (xor 1,2,4,8 within seg group)
        float tmax = s;
        #pragma unroll
        for (int off = 1; off < 16; off <<= 1)
            tmax = fmaxf(tmax, __shfl_xor(tmax, off));
        float m_new = fmaxf(m_g, tmax);
        float alpha = __expf(m_g - m_new);
        float p     = __expf(s - m_new);
        float tsum = p;
        #pragma unroll
        for (int off = 1; off < 16; off <<= 1)
            tsum += __shfl_xor(tsum, off);
        l_g = l_g * alpha + tsum;
        m_g = m_new;

        p_lds[w][t_s][seg] = p;
        if (t_s == 0) a_lds[w][seg] = alpha;

        WAIT_VM0();     // V_i landed in Y

        if (has_next) { // K_{i+1} -> X (scores done; its latency hides behind PV)
            fence_sched();
            #pragma unroll
            for (int r = 0; r < 8; ++r)
                glds16(kbase + (size_t)pgn[r] * KVROW + csw[r & 3], &kx[w][r * 2][0]);
            fence_sched();
        }

        // PV: lane owns d-pair dp; p broadcast per token; V read swizzled
        float a0 = a_lds[w][0], a1 = a_lds[w][1], a2 = a_lds[w][2], a3 = a_lds[w][3];
        o00 *= a0; o01 *= a0; o10 *= a1; o11 *= a1;
        o20 *= a2; o21 *= a2; o30 *= a3; o31 *= a3;
        #pragma unroll
        for (int t = 0; t < TILE_T; ++t) {
            int pc = (((lane >> 1) ^ (t & 7)) << 2) + ((lane & 1) << 1);
            float2 vv = *(const float2*)&ky[w][t][pc];
            float4 pp = *(const float4*)&p_lds[w][t][0];   // broadcast
            o00 = fmaf(pp.x, vv.x, o00); o01 = fmaf(pp.x, vv.y, o01);
            o10 = fmaf(pp.y, vv.x, o10); o11 = fmaf(pp.y, vv.y, o11);
            o20 = fmaf(pp.z, vv.x, o20); o21 = fmaf(pp.z, vv.y, o21);
            o30 = fmaf(pp.w, vv.x, o30); o31 = fmaf(pp.w, vv.y, o31);
        }

        if (has_next) { // V_{i+1} -> Y (PV done; its latency hides behind next scores)
            fence_sched();
            #pragma unroll
            for (int r = 0; r < 8; ++r)
                glds16(vbase + (size_t)pgn[r] * KVROW + csw[r & 3], &ky[w][r * 2][0]);
            fence_sched();
        }
    }

    // cross-wave combine within block: each wave dumps into ITS OWN kx region
    {
        float* ow = &kx[w][0][0];          // 512 floats used of 2048
        ow[0 * HD + dp] = o00; ow[0 * HD + dp + 1] = o01;
        ow[1 * HD + dp] = o10; ow[1 * HD + dp + 1] = o11;
        ow[2 * HD + dp] = o20; ow[2 * HD + dp + 1] = o21;
        ow[3 * HD + dp] = o30; ow[3 * HD + dp + 1] = o31;
        if (t_s == 0) { ml_lds[w][seg][0] = m_g; ml_lds[w][seg][1] = l_g; }
    }
    __syncthreads();

    {
        int g  = tid >> 6;
        int d2 = (tid & 63) * 2;
        float M = fmaxf(fmaxf(ml_lds[0][g][0], ml_lds[1][g][0]),
                        fmaxf(ml_lds[2][g][0], ml_lds[3][g][0]));
        float L = 0.0f, O0 = 0.0f, O1 = 0.0f;
        #pragma unroll
        for (int wv = 0; wv < NWAVE; ++wv) {
            float sc = __expf(ml_lds[wv][g][0] - M);   // idle wave contributes 0
            L  += ml_lds[wv][g][1] * sc;
            const float* owv = &kx[wv][0][0];
            O0 += owv[g * HD + d2]     * sc;
            O1 += owv[g * HD + d2 + 1] * sc;
        }
        pb[g * HD + d2]     = O0;          // unnormalized partial
        pb[g * HD + d2 + 1] = O1;
        if ((tid & 63) == 0) { pb[512 + g] = M; pb[516 + g] = L; }
    }
}

__global__ __launch_bounds__(256) void attn_combine_kernel(
    const float* __restrict__ part, float* __restrict__ out)
{
    const int bid = blockIdx.x;        // b*NKVH + kvh
    const int tid = threadIdx.x;
    const int g  = tid >> 6;
    const int d2 = (tid & 63) * 2;
    const int b   = bid / NKVH;
    const int kvh = bid % NKVH;
    const float* pb = part + (size_t)bid * NSPLIT * PART_STRIDE;

    float M = -1e30f;
    #pragma unroll
    for (int cc = 0; cc < NSPLIT; ++cc)
        M = fmaxf(M, pb[cc * PART_STRIDE + 512 + g]);
    float L = 0.0f, O0 = 0.0f, O1 = 0.0f;
    #pragma unroll
    for (int cc = 0; cc < NSPLIT; ++cc) {
        float mc = pb[cc * PART_STRIDE + 512 + g];
        float sc = __expf(mc - M);                    // empty chunk -> 0
        L  += pb[cc * PART_STRIDE + 516 + g] * sc;
        O0 += pb[cc * PART_STRIDE + g * HD + d2]     * sc;
        O1 += pb[cc * PART_STRIDE + g * HD + d2 + 1] * sc;
    }
    float inv = 1.0f / L;                             // chunk 0 non-empty -> L > 0
    const int h = kvh * NG + g;
    out[((size_t)b * NH + h) * HD + d2]     = O0 * inv;
    out[((size_t)b * NH + h) * HD + d2 + 1] = O1 * inv;
}

extern "C" void kernel_launch(void* const* d_in, const int* in_sizes, int n_in,
                              void* d_out, int out_size, void* d_ws, size_t ws_size,
                              hipStream_t stream)
{
    const float* q   = (const float*)d_in[0];
    const float* kc  = (const float*)d_in[1];
    const float* vc  = (const float*)d_in[2];
    const int*   kvl = (const int*)d_in[3];
    const int*   bt  = (const int*)d_in[4];
    float* part = (float*)d_ws;   // 16*8*16*520*4 B = 4.06 MB of ws used

    attn_partial_kernel<<<NB * NKVH * NSPLIT, 256, 0, stream>>>(q, kc, vc, kvl, bt, part);
    attn_combine_kernel<<<NB * NKVH, 256, 0, stream>>>(part, (float*)d_out);
}